// Round 4
// baseline (331.811 us; speedup 1.0000x reference)
//
#include <hip/hip_runtime.h>
#include <hip/hip_bf16.h>

typedef unsigned short u16;
typedef __bf16 bf16x8 __attribute__((ext_vector_type(8)));
typedef float f32x4 __attribute__((ext_vector_type(4)));

#define N_ROWS 8192
#define M_ROWS 4096
#define E_DIM  512
#define KSPLIT 4

// ---------- helpers ----------
__device__ __forceinline__ u16 f2bf(float f) {
    unsigned u = __float_as_uint(f);
    u += 0x7FFF + ((u >> 16) & 1);   // RNE
    return (u16)(u >> 16);
}
__device__ __forceinline__ float bf2f(u16 u) {
    return __uint_as_float(((unsigned)u) << 16);
}

#define GLD16(gp, lp) \
    __builtin_amdgcn_global_load_lds((const __attribute__((address_space(1))) void*)(gp), \
                                     (__attribute__((address_space(3))) void*)(lp), 16, 0, 0)

// ---------- cast fp32 -> bf16, 4 elems/thread ----------
__global__ __launch_bounds__(256)
void cast_bf(const float* __restrict__ in, u16* __restrict__ out, int n4) {
    int i = blockIdx.x * 256 + threadIdx.x;
    if (i < n4) {
        float4 f = reinterpret_cast<const float4*>(in)[i];
        ushort4 o;
        o.x = f2bf(f.x); o.y = f2bf(f.y); o.z = f2bf(f.z); o.w = f2bf(f.w);
        reinterpret_cast<ushort4*>(out)[i] = o;
    }
}

// ---------- bf16 tiled transpose: out[c][r] = in[r][c]; R,C multiples of 64 ----------
__global__ __launch_bounds__(256)
void transpose_bf(const u16* __restrict__ in, u16* __restrict__ out, int R, int C) {
    __shared__ u16 t[64][72];   // stride 72 u16 = 144 B (16B-aligned rows)
    const int r0 = blockIdx.y * 64, c0 = blockIdx.x * 64;
    const int tid = threadIdx.x;
    const int lr = tid >> 2, lc = (tid & 3) * 16;
    const u16* src = in + (size_t)(r0 + lr) * C + c0 + lc;
    *reinterpret_cast<uint4*>(&t[lr][lc])     = *reinterpret_cast<const uint4*>(src);
    *reinterpret_cast<uint4*>(&t[lr][lc + 8]) = *reinterpret_cast<const uint4*>(src + 8);
    __syncthreads();
    u16 tmp[16];
#pragma unroll
    for (int j = 0; j < 16; ++j) tmp[j] = t[lc + j][lr];
    u16* dst = out + (size_t)(c0 + lr) * R + r0 + lc;
    *reinterpret_cast<uint4*>(dst)     = *reinterpret_cast<uint4*>(&tmp[0]);
    *reinterpret_cast<uint4*>(dst + 8) = *reinterpret_cast<uint4*>(&tmp[8]);
}

// ---------- 128x128 MFMA GEMM body, single-barrier double-buffered pipeline ----------
// C[i][j] = sum_k A[i][k]*B[j][k]; A,B bf16 K-contiguous.
// mode: 0 = fp32 row-major, 1 = bf16 row-major
__device__ __forceinline__
void gemm128_body(const u16* __restrict__ A, int lda,
                  const u16* __restrict__ B, int ldb,
                  void* __restrict__ C, int ldc, int K,
                  int row0, int col0, int mode) {
    __shared__ u16 sA[2][128 * 32];   // row-major, unpadded (global_load_lds layout constraint)
    __shared__ u16 sB[2][128 * 32];

    const int tid  = threadIdx.x;
    const int wave = tid >> 6, lane = tid & 63;
    const int quad = lane >> 4, m16 = lane & 15;
    const int wr = (wave & 1) * 64;       // wave's 64-row quadrant
    const int wc = (wave >> 1) * 64;      // wave's 64-col quadrant

    // staging: wave w stages 16-row chunks {w, w+4}; lane -> (row=L/4, k=(L%4)*8)
    const int srow  = lane >> 2;
    const int skoff = (lane & 3) * 8;
    const u16* ag0 = A + (size_t)(row0 + wave * 16 + srow) * lda + skoff;
    const u16* ag1 = ag0 + (size_t)64 * lda;
    const u16* bg0 = B + (size_t)(col0 + wave * 16 + srow) * ldb + skoff;
    const u16* bg1 = bg0 + (size_t)64 * ldb;
    const int lo0 = (wave * 16) * 32;
    const int lo1 = (wave * 16 + 64) * 32;

    f32x4 acc[4][4];
#pragma unroll
    for (int i = 0; i < 4; ++i)
#pragma unroll
        for (int j = 0; j < 4; ++j) acc[i][j] = (f32x4){0.f, 0.f, 0.f, 0.f};

    // prologue: stage k=0 into buffer 0
    GLD16(ag0, &sA[0][lo0]); GLD16(ag1, &sA[0][lo1]);
    GLD16(bg0, &sB[0][lo0]); GLD16(bg1, &sB[0][lo1]);

    int kb = 0;
    for (int k0 = 0; k0 < K; k0 += 32, kb ^= 1) {
        __syncthreads();   // drains vmcnt: buf[kb] landed; lgkmcnt: prior reads of buf[kb^1] done
        const int kn = (k0 + 32 < K) ? (k0 + 32) : 0;   // last iter: harmless reload
        GLD16(ag0 + kn, &sA[kb ^ 1][lo0]); GLD16(ag1 + kn, &sA[kb ^ 1][lo1]);
        GLD16(bg0 + kn, &sB[kb ^ 1][lo0]); GLD16(bg1 + kn, &sB[kb ^ 1][lo1]);

        bf16x8 a[4], b[4];
#pragma unroll
        for (int i = 0; i < 4; ++i)
            a[i] = *reinterpret_cast<const bf16x8*>(&sA[kb][(wr + i * 16 + m16) * 32 + quad * 8]);
#pragma unroll
        for (int j = 0; j < 4; ++j)
            b[j] = *reinterpret_cast<const bf16x8*>(&sB[kb][(wc + j * 16 + m16) * 32 + quad * 8]);
#pragma unroll
        for (int i = 0; i < 4; ++i)
#pragma unroll
            for (int j = 0; j < 4; ++j)
                acc[i][j] = __builtin_amdgcn_mfma_f32_16x16x32_bf16(a[i], b[j], acc[i][j], 0, 0, 0);
    }

    // epilogue: C/D layout col=lane&15, row=quad*4+r (HW-verified)
#pragma unroll
    for (int i = 0; i < 4; ++i) {
        const int rbase = row0 + wr + i * 16 + quad * 4;
#pragma unroll
        for (int j = 0; j < 4; ++j) {
            const int c = col0 + wc + j * 16 + m16;
#pragma unroll
            for (int r = 0; r < 4; ++r) {
                const float v = acc[i][j][r];
                const int rr = rbase + r;
                if (mode == 0) {
                    reinterpret_cast<float*>(C)[(size_t)rr * ldc + c] = v;
                } else {
                    reinterpret_cast<u16*>(C)[(size_t)rr * ldc + c] = f2bf(v);
                }
            }
        }
    }
}

// ---------- batched projection GEMMs (grid.z picks descriptor) ----------
struct ProjArgs {
    const u16* A[3];
    const u16* B[3];
    void*      C[3];
    int        rows[3];
    int        mode[3];
    int        ldc[3];
};

__global__ __launch_bounds__(256)
void proj_gemm(ProjArgs p) {
    const int z = blockIdx.z;
    const int row0 = blockIdx.y * 128;
    if (row0 >= p.rows[z]) return;
    gemm128_body(p.A[z], E_DIM, p.B[z], E_DIM, p.C[z], p.ldc[z], E_DIM,
                 row0, blockIdx.x * 128, p.mode[z]);
}

// ---------- main GEMM (score / PV with optional split-K over grid.z) ----------
__global__ __launch_bounds__(256)
void gemm_main(const u16* __restrict__ A, int lda,
               const u16* __restrict__ B, int ldb,
               void* __restrict__ C, int ldc, int Kslice,
               long long cstride_bytes, int mode) {
    const int z = blockIdx.z;
    const u16* Az = A + (long long)z * Kslice;
    const u16* Bz = B + (long long)z * Kslice;
    void* Cz = (char*)C + (long long)z * cstride_bytes;
    gemm128_body(Az, lda, Bz, ldb, Cz, ldc, Kslice,
                 blockIdx.y * 128, blockIdx.x * 128, mode);
}

// ---------- self attention score: dot(T[n], vcode[n]) ----------
__global__ __launch_bounds__(256)
void self_dot(const u16* __restrict__ q, const u16* __restrict__ k,
              float* __restrict__ selfS) {
    const int wave = threadIdx.x >> 6, lane = threadIdx.x & 63;
    const int row = blockIdx.x * 4 + wave;
    const uint4 qa = *reinterpret_cast<const uint4*>(q + (size_t)row * E_DIM + lane * 8);
    const uint4 ka = *reinterpret_cast<const uint4*>(k + (size_t)row * E_DIM + lane * 8);
    unsigned qu[4] = {qa.x, qa.y, qa.z, qa.w};
    unsigned ku[4] = {ka.x, ka.y, ka.z, ka.w};
    float s = 0.f;
#pragma unroll
    for (int i = 0; i < 4; ++i) {
        s += bf2f((u16)(qu[i] & 0xFFFF)) * bf2f((u16)(ku[i] & 0xFFFF));
        s += bf2f((u16)(qu[i] >> 16))    * bf2f((u16)(ku[i] >> 16));
    }
#pragma unroll
    for (int off = 32; off; off >>= 1) s += __shfl_down(s, off);
    if (lane == 0) selfS[row] = s;
}

// ---------- row softmax over bf16 scores [self, row]; bf16 weights in place ----------
__global__ __launch_bounds__(256)
void softmax_row_bf(u16* __restrict__ S, const float* __restrict__ selfS,
                    float* __restrict__ w0) {
    __shared__ float lds[8];
    const int n = blockIdx.x, t = threadIdx.x;
    const int lane = t & 63, wave = t >> 6;
    u16* row = S + (size_t)n * M_ROWS;

    uint4 raw[2];
    raw[0] = reinterpret_cast<const uint4*>(row)[t];
    raw[1] = reinterpret_cast<const uint4*>(row)[t + 256];
    float v[16];
#pragma unroll
    for (int h = 0; h < 2; ++h) {
        unsigned u0 = raw[h].x, u1 = raw[h].y, u2 = raw[h].z, u3 = raw[h].w;
        v[h * 8 + 0] = bf2f((u16)(u0 & 0xFFFF)); v[h * 8 + 1] = bf2f((u16)(u0 >> 16));
        v[h * 8 + 2] = bf2f((u16)(u1 & 0xFFFF)); v[h * 8 + 3] = bf2f((u16)(u1 >> 16));
        v[h * 8 + 4] = bf2f((u16)(u2 & 0xFFFF)); v[h * 8 + 5] = bf2f((u16)(u2 >> 16));
        v[h * 8 + 6] = bf2f((u16)(u3 & 0xFFFF)); v[h * 8 + 7] = bf2f((u16)(u3 >> 16));
    }
    const float s0 = selfS[n];

    float lmax = s0;
#pragma unroll
    for (int i = 0; i < 16; ++i) lmax = fmaxf(lmax, v[i]);
#pragma unroll
    for (int off = 32; off; off >>= 1) lmax = fmaxf(lmax, __shfl_down(lmax, off));
    if (lane == 0) lds[wave] = lmax;
    __syncthreads();
    const float gmax = fmaxf(fmaxf(lds[0], lds[1]), fmaxf(lds[2], lds[3]));
    __syncthreads();

    const float invT = (float)(1.0 / 22.627416997969522);
    float lsum = 0.f;
#pragma unroll
    for (int i = 0; i < 16; ++i) { v[i] = expf((v[i] - gmax) * invT); lsum += v[i]; }
#pragma unroll
    for (int off = 32; off; off >>= 1) lsum += __shfl_down(lsum, off);
    if (lane == 0) lds[wave] = lsum;
    __syncthreads();
    const float p0 = expf((s0 - gmax) * invT);
    const float gsum = lds[0] + lds[1] + lds[2] + lds[3] + p0;
    const float inv = 1.f / gsum;

#pragma unroll
    for (int h = 0; h < 2; ++h) {
        unsigned o0 = (unsigned)f2bf(v[h*8+0] * inv) | ((unsigned)f2bf(v[h*8+1] * inv) << 16);
        unsigned o1 = (unsigned)f2bf(v[h*8+2] * inv) | ((unsigned)f2bf(v[h*8+3] * inv) << 16);
        unsigned o2 = (unsigned)f2bf(v[h*8+4] * inv) | ((unsigned)f2bf(v[h*8+5] * inv) << 16);
        unsigned o3 = (unsigned)f2bf(v[h*8+6] * inv) | ((unsigned)f2bf(v[h*8+7] * inv) << 16);
        reinterpret_cast<uint4*>(row)[h == 0 ? t : t + 256] = (uint4){o0, o1, o2, o3};
    }
    if (t == 0) w0[n] = p0 * inv;
}

// ---------- epilogue: LN(w0*v_value + sum_z O_z + v_code) ----------
__global__ __launch_bounds__(256)
void final_ln(const u16* __restrict__ O /* KSPLIT bf16 slices */,
              const float* __restrict__ vval,
              const float* __restrict__ w0, const float* __restrict__ vcode,
              const float* __restrict__ gamma, const float* __restrict__ beta,
              float* __restrict__ out) {
    __shared__ float lds[8];
    const int n = blockIdx.x, t = threadIdx.x;
    const int lane = t & 63, wave = t >> 6;
    const size_t base = (size_t)n * E_DIM;
    const size_t NE = (size_t)N_ROWS * E_DIM;
    const float a = w0[n];

    float o0 = 0.f, o1 = 0.f;
#pragma unroll
    for (int z = 0; z < KSPLIT; ++z) {
        o0 += bf2f(O[z * NE + base + t]);
        o1 += bf2f(O[z * NE + base + t + 256]);
    }
    float x0 = fmaf(a, vval[base + t],       o0) + vcode[base + t];
    float x1 = fmaf(a, vval[base + t + 256], o1) + vcode[base + t + 256];

    float s = x0 + x1;
#pragma unroll
    for (int off = 32; off; off >>= 1) s += __shfl_down(s, off);
    if (lane == 0) lds[wave] = s;
    __syncthreads();
    const float mu = (lds[0] + lds[1] + lds[2] + lds[3]) * (1.0f / E_DIM);
    __syncthreads();

    const float d0 = x0 - mu, d1 = x1 - mu;
    float vs = d0 * d0 + d1 * d1;
#pragma unroll
    for (int off = 32; off; off >>= 1) vs += __shfl_down(vs, off);
    if (lane == 0) lds[wave] = vs;
    __syncthreads();
    const float var = (lds[0] + lds[1] + lds[2] + lds[3]) * (1.0f / E_DIM);
    const float rs = rsqrtf(var + 1e-6f);

    out[base + t]       = d0 * rs * gamma[t]       + beta[t];
    out[base + t + 256] = d1 * rs * gamma[t + 256] + beta[t + 256];
}

// ---------- workspace layout (bytes; total ~150 MiB) ----------
#define OFF_VCODEBF 0ull
#define OFF_OBSBF   8388608ull
#define OFF_WQ      12582912ull
#define OFF_WK      13107200ull
#define OFF_WV      13631488ull
#define OFF_WQT     14155776ull
#define OFF_WKT     14680064ull
#define OFF_WQKT    15204352ull
#define OFF_TBF     15728640ull
#define OFF_OBSV    24117248ull
#define OFF_OBSVT   28311552ull
#define OFF_VVAL    32505856ull
#define OFF_S       49283072ull
#define OFF_O       116391936ull
#define OFF_W0      149946368ull
#define OFF_SELF    149979136ull

extern "C" void kernel_launch(void* const* d_in, const int* in_sizes, int n_in,
                              void* d_out, int out_size, void* d_ws, size_t ws_size,
                              hipStream_t stream) {
    const float* v_code   = (const float*)d_in[0];
    const float* obs_code = (const float*)d_in[1];
    const float* Wq       = (const float*)d_in[2];
    const float* Wk       = (const float*)d_in[3];
    const float* Wv       = (const float*)d_in[4];
    const float* gamma    = (const float*)d_in[5];
    const float* beta     = (const float*)d_in[6];
    float* out = (float*)d_out;
    char* ws = (char*)d_ws;

    u16* vcode_bf = (u16*)(ws + OFF_VCODEBF);
    u16* obs_bf   = (u16*)(ws + OFF_OBSBF);
    u16* wq_bf    = (u16*)(ws + OFF_WQ);
    u16* wk_bf    = (u16*)(ws + OFF_WK);
    u16* wv_bf    = (u16*)(ws + OFF_WV);
    u16* wqT      = (u16*)(ws + OFF_WQT);
    u16* wkT      = (u16*)(ws + OFF_WKT);
    u16* wqkT     = (u16*)(ws + OFF_WQKT);
    u16* t_bf     = (u16*)(ws + OFF_TBF);
    u16* obsv_bf  = (u16*)(ws + OFF_OBSV);
    u16* obsvT_bf = (u16*)(ws + OFF_OBSVT);
    float* vval   = (float*)(ws + OFF_VVAL);
    u16* S        = (u16*)(ws + OFF_S);
    u16* O        = (u16*)(ws + OFF_O);
    float* w0     = (float*)(ws + OFF_W0);
    float* selfS  = (float*)(ws + OFF_SELF);

    // 1. casts
    cast_bf<<<N_ROWS * E_DIM / 4 / 256, 256, 0, stream>>>(v_code, vcode_bf, N_ROWS * E_DIM / 4);
    cast_bf<<<M_ROWS * E_DIM / 4 / 256, 256, 0, stream>>>(obs_code, obs_bf, M_ROWS * E_DIM / 4);
    cast_bf<<<E_DIM * E_DIM / 4 / 256, 256, 0, stream>>>(Wq, wq_bf, E_DIM * E_DIM / 4);
    cast_bf<<<E_DIM * E_DIM / 4 / 256, 256, 0, stream>>>(Wk, wk_bf, E_DIM * E_DIM / 4);
    cast_bf<<<E_DIM * E_DIM / 4 / 256, 256, 0, stream>>>(Wv, wv_bf, E_DIM * E_DIM / 4);

    // 2. transpose Wq, Wk (coalesced LDS transpose; 512x512 each)
    transpose_bf<<<dim3(8, 8), 256, 0, stream>>>(wq_bf, wqT, E_DIM, E_DIM);
    transpose_bf<<<dim3(8, 8), 256, 0, stream>>>(wk_bf, wkT, E_DIM, E_DIM);

    // 3. WqkT = (Wq^T Wk)^T = gemm_bt(WkT, WqT)  [512x512]
    gemm_main<<<dim3(4, 4, 1), 256, 0, stream>>>(wkT, E_DIM, wqT, E_DIM, wqkT, E_DIM, E_DIM, 0, 1);

    // 4. projections: vval = vcode@Wv^T (fp32), obsv = obs@Wv^T (bf16), T = vcode@Wqk (bf16)
    ProjArgs p;
    p.A[0] = vcode_bf; p.B[0] = wv_bf; p.C[0] = vval;    p.rows[0] = N_ROWS; p.mode[0] = 0; p.ldc[0] = E_DIM;
    p.A[1] = obs_bf;   p.B[1] = wv_bf; p.C[1] = obsv_bf; p.rows[1] = M_ROWS; p.mode[1] = 1; p.ldc[1] = E_DIM;
    p.A[2] = vcode_bf; p.B[2] = wqkT;  p.C[2] = t_bf;    p.rows[2] = N_ROWS; p.mode[2] = 1; p.ldc[2] = E_DIM;
    proj_gemm<<<dim3(E_DIM / 128, N_ROWS / 128, 3), 256, 0, stream>>>(p);

    // 5. transpose obsv -> obsvT [512 x 4096] (coalesced both sides)
    transpose_bf<<<dim3(E_DIM / 64, M_ROWS / 64), 256, 0, stream>>>(obsv_bf, obsvT_bf, M_ROWS, E_DIM);

    // 6. self score: dot(T[n], vcode[n])
    self_dot<<<N_ROWS / 4, 256, 0, stream>>>(t_bf, vcode_bf, selfS);

    // 7. cross scores S = T @ obs^T  [8192 x 4096], bf16 out
    gemm_main<<<dim3(M_ROWS / 128, N_ROWS / 128, 1), 256, 0, stream>>>(
        t_bf, E_DIM, obs_bf, E_DIM, S, M_ROWS, E_DIM, 0, 1);

    // 8. softmax -> bf16 weights in place
    softmax_row_bf<<<N_ROWS, 256, 0, stream>>>(S, selfS, w0);

    // 9. O_z = W[:, z*1024:(z+1)*1024] @ V_obs[z*1024:(z+1)*1024, :]  (split-K=4, bf16 slices)
    gemm_main<<<dim3(E_DIM / 128, N_ROWS / 128, KSPLIT), 256, 0, stream>>>(
        S, M_ROWS, obsvT_bf, M_ROWS, O, E_DIM, M_ROWS / KSPLIT,
        (long long)N_ROWS * E_DIM * 2, 1);

    // 10. residual + LayerNorm (sums the KSPLIT PV slices)
    final_ln<<<N_ROWS, 256, 0, stream>>>(O, vval, w0, v_code, gamma, beta, out);
}

// Round 5
// 287.424 us; speedup vs baseline: 1.1544x; 1.1544x over previous
//
#include <hip/hip_runtime.h>
#include <hip/hip_bf16.h>

typedef unsigned short u16;
typedef __bf16 bf16x8 __attribute__((ext_vector_type(8)));
typedef float f32x4 __attribute__((ext_vector_type(4)));

#define N_ROWS 8192
#define M_ROWS 4096
#define E_DIM  512
#define KSPLIT 4

// ---------- helpers ----------
__device__ __forceinline__ u16 f2bf(float f) {
    unsigned u = __float_as_uint(f);
    u += 0x7FFF + ((u >> 16) & 1);   // RNE
    return (u16)(u >> 16);
}
__device__ __forceinline__ float bf2f(u16 u) {
    return __uint_as_float(((unsigned)u) << 16);
}

#define GLD16(gp, lp) \
    __builtin_amdgcn_global_load_lds((const __attribute__((address_space(1))) void*)(gp), \
                                     (__attribute__((address_space(3))) void*)(lp), 16, 0, 0)

// ---------- cast fp32 -> bf16, 4 elems/thread ----------
__global__ __launch_bounds__(256)
void cast_bf(const float* __restrict__ in, u16* __restrict__ out, int n4) {
    int i = blockIdx.x * 256 + threadIdx.x;
    if (i < n4) {
        float4 f = reinterpret_cast<const float4*>(in)[i];
        ushort4 o;
        o.x = f2bf(f.x); o.y = f2bf(f.y); o.z = f2bf(f.z); o.w = f2bf(f.w);
        reinterpret_cast<ushort4*>(out)[i] = o;
    }
}

// ---------- bf16 tiled transpose: out[c][r] = in[r][c]; R,C multiples of 64 ----------
__global__ __launch_bounds__(256)
void transpose_bf(const u16* __restrict__ in, u16* __restrict__ out, int R, int C) {
    __shared__ u16 t[64][72];
    const int r0 = blockIdx.y * 64, c0 = blockIdx.x * 64;
    const int tid = threadIdx.x;
    const int lr = tid >> 2, lc = (tid & 3) * 16;
    const u16* src = in + (size_t)(r0 + lr) * C + c0 + lc;
    *reinterpret_cast<uint4*>(&t[lr][lc])     = *reinterpret_cast<const uint4*>(src);
    *reinterpret_cast<uint4*>(&t[lr][lc + 8]) = *reinterpret_cast<const uint4*>(src + 8);
    __syncthreads();
    u16 tmp[16];
#pragma unroll
    for (int j = 0; j < 16; ++j) tmp[j] = t[lc + j][lr];
    u16* dst = out + (size_t)(c0 + lr) * R + r0 + lc;
    *reinterpret_cast<uint4*>(dst)     = *reinterpret_cast<uint4*>(&tmp[0]);
    *reinterpret_cast<uint4*>(dst + 8) = *reinterpret_cast<uint4*>(&tmp[8]);
}

// ---------- 128x256 MFMA GEMM body, single-barrier double-buffered pipeline ----------
// C[i][j] = sum_k A[i][k]*B[j][k]; A,B bf16 K-contiguous.
// Per wave: 64 rows x 128 cols = 4x8 fragments, 32 MFMA / K-step.
// mode: 0 = fp32 row-major, 1 = bf16 row-major
__device__ __forceinline__
void gemm_wide_body(const u16* __restrict__ A, int lda,
                    const u16* __restrict__ B, int ldb,
                    void* __restrict__ C, int ldc, int K,
                    int row0, int col0, int mode) {
    __shared__ u16 sA[2][128 * 32];   // 8 KB per buffer
    __shared__ u16 sB[2][256 * 32];   // 16 KB per buffer

    const int tid  = threadIdx.x;
    const int wave = tid >> 6, lane = tid & 63;
    const int quad = lane >> 4, m16 = lane & 15;
    const int wr = (wave & 1) * 64;       // wave's 64-row half
    const int wc = (wave >> 1) * 128;     // wave's 128-col half

    // staging: lane -> (row = L/4, k = (L%4)*8); wave w covers 16-row chunks at stride 64
    const int srow  = lane >> 2;
    const int skoff = (lane & 3) * 8;
    const u16* ag0 = A + (size_t)(row0 + wave * 16 + srow) * lda + skoff;
    const u16* ag1 = ag0 + (size_t)64 * lda;
    const u16* bg0 = B + (size_t)(col0 + wave * 16 + srow) * ldb + skoff;
    const u16* bg1 = bg0 + (size_t)64 * ldb;
    const u16* bg2 = bg0 + (size_t)128 * ldb;
    const u16* bg3 = bg0 + (size_t)192 * ldb;
    const int loa0 = (wave * 16) * 32;
    const int loa1 = (wave * 16 + 64) * 32;
    const int lob0 = (wave * 16) * 32;
    const int lob1 = (wave * 16 + 64) * 32;
    const int lob2 = (wave * 16 + 128) * 32;
    const int lob3 = (wave * 16 + 192) * 32;

    f32x4 acc[4][8];
#pragma unroll
    for (int i = 0; i < 4; ++i)
#pragma unroll
        for (int j = 0; j < 8; ++j) acc[i][j] = (f32x4){0.f, 0.f, 0.f, 0.f};

    // prologue: stage k=0 into buffer 0
    GLD16(ag0, &sA[0][loa0]); GLD16(ag1, &sA[0][loa1]);
    GLD16(bg0, &sB[0][lob0]); GLD16(bg1, &sB[0][lob1]);
    GLD16(bg2, &sB[0][lob2]); GLD16(bg3, &sB[0][lob3]);

    int kb = 0;
    for (int k0 = 0; k0 < K; k0 += 32, kb ^= 1) {
        __syncthreads();   // buf[kb] data landed; prior reads of buf[kb^1] done
        const int kn = (k0 + 32 < K) ? (k0 + 32) : 0;   // last iter: harmless reload
        GLD16(ag0 + kn, &sA[kb ^ 1][loa0]); GLD16(ag1 + kn, &sA[kb ^ 1][loa1]);
        GLD16(bg0 + kn, &sB[kb ^ 1][lob0]); GLD16(bg1 + kn, &sB[kb ^ 1][lob1]);
        GLD16(bg2 + kn, &sB[kb ^ 1][lob2]); GLD16(bg3 + kn, &sB[kb ^ 1][lob3]);

        bf16x8 a[4], b[8];
#pragma unroll
        for (int i = 0; i < 4; ++i)
            a[i] = *reinterpret_cast<const bf16x8*>(&sA[kb][(wr + i * 16 + m16) * 32 + quad * 8]);
#pragma unroll
        for (int j = 0; j < 8; ++j)
            b[j] = *reinterpret_cast<const bf16x8*>(&sB[kb][(wc + j * 16 + m16) * 32 + quad * 8]);
#pragma unroll
        for (int i = 0; i < 4; ++i)
#pragma unroll
            for (int j = 0; j < 8; ++j)
                acc[i][j] = __builtin_amdgcn_mfma_f32_16x16x32_bf16(a[i], b[j], acc[i][j], 0, 0, 0);
    }

    // epilogue: C/D layout col=lane&15, row=quad*4+r (HW-verified)
#pragma unroll
    for (int i = 0; i < 4; ++i) {
        const int rbase = row0 + wr + i * 16 + quad * 4;
#pragma unroll
        for (int j = 0; j < 8; ++j) {
            const int c = col0 + wc + j * 16 + m16;
#pragma unroll
            for (int r = 0; r < 4; ++r) {
                const float v = acc[i][j][r];
                const int rr = rbase + r;
                if (mode == 0) {
                    reinterpret_cast<float*>(C)[(size_t)rr * ldc + c] = v;
                } else {
                    reinterpret_cast<u16*>(C)[(size_t)rr * ldc + c] = f2bf(v);
                }
            }
        }
    }
}

// ---------- batched projection GEMMs (grid.z picks descriptor) ----------
struct ProjArgs {
    const u16* A[3];
    const u16* B[3];
    void*      C[3];
    int        rows[3];
    int        mode[3];
    int        ldc[3];
};

__global__ __launch_bounds__(256, 2)
void proj_gemm(ProjArgs p) {
    const int z = blockIdx.z;
    const int row0 = blockIdx.y * 128;
    if (row0 >= p.rows[z]) return;
    gemm_wide_body(p.A[z], E_DIM, p.B[z], E_DIM, p.C[z], p.ldc[z], E_DIM,
                   row0, blockIdx.x * 256, p.mode[z]);
}

// ---------- main GEMM (score / PV with optional split-K over grid.z) ----------
__global__ __launch_bounds__(256, 2)
void gemm_main(const u16* __restrict__ A, int lda,
               const u16* __restrict__ B, int ldb,
               void* __restrict__ C, int ldc, int Kslice,
               long long cstride_bytes, int mode) {
    const int z = blockIdx.z;
    const u16* Az = A + (long long)z * Kslice;
    const u16* Bz = B + (long long)z * Kslice;
    void* Cz = (char*)C + (long long)z * cstride_bytes;
    gemm_wide_body(Az, lda, Bz, ldb, Cz, ldc, Kslice,
                   blockIdx.y * 128, blockIdx.x * 256, mode);
}

// ---------- self attention score: dot(T[n], vcode[n]) ----------
__global__ __launch_bounds__(256)
void self_dot(const u16* __restrict__ q, const u16* __restrict__ k,
              float* __restrict__ selfS) {
    const int wave = threadIdx.x >> 6, lane = threadIdx.x & 63;
    const int row = blockIdx.x * 4 + wave;
    const uint4 qa = *reinterpret_cast<const uint4*>(q + (size_t)row * E_DIM + lane * 8);
    const uint4 ka = *reinterpret_cast<const uint4*>(k + (size_t)row * E_DIM + lane * 8);
    unsigned qu[4] = {qa.x, qa.y, qa.z, qa.w};
    unsigned ku[4] = {ka.x, ka.y, ka.z, ka.w};
    float s = 0.f;
#pragma unroll
    for (int i = 0; i < 4; ++i) {
        s += bf2f((u16)(qu[i] & 0xFFFF)) * bf2f((u16)(ku[i] & 0xFFFF));
        s += bf2f((u16)(qu[i] >> 16))    * bf2f((u16)(ku[i] >> 16));
    }
#pragma unroll
    for (int off = 32; off; off >>= 1) s += __shfl_down(s, off);
    if (lane == 0) selfS[row] = s;
}

// ---------- row softmax over bf16 scores [self, row]; bf16 weights in place ----------
__global__ __launch_bounds__(256)
void softmax_row_bf(u16* __restrict__ S, const float* __restrict__ selfS,
                    float* __restrict__ w0) {
    __shared__ float lds[8];
    const int n = blockIdx.x, t = threadIdx.x;
    const int lane = t & 63, wave = t >> 6;
    u16* row = S + (size_t)n * M_ROWS;

    uint4 raw[2];
    raw[0] = reinterpret_cast<const uint4*>(row)[t];
    raw[1] = reinterpret_cast<const uint4*>(row)[t + 256];
    float v[16];
#pragma unroll
    for (int h = 0; h < 2; ++h) {
        unsigned u0 = raw[h].x, u1 = raw[h].y, u2 = raw[h].z, u3 = raw[h].w;
        v[h * 8 + 0] = bf2f((u16)(u0 & 0xFFFF)); v[h * 8 + 1] = bf2f((u16)(u0 >> 16));
        v[h * 8 + 2] = bf2f((u16)(u1 & 0xFFFF)); v[h * 8 + 3] = bf2f((u16)(u1 >> 16));
        v[h * 8 + 4] = bf2f((u16)(u2 & 0xFFFF)); v[h * 8 + 5] = bf2f((u16)(u2 >> 16));
        v[h * 8 + 6] = bf2f((u16)(u3 & 0xFFFF)); v[h * 8 + 7] = bf2f((u16)(u3 >> 16));
    }
    const float s0 = selfS[n];

    float lmax = s0;
#pragma unroll
    for (int i = 0; i < 16; ++i) lmax = fmaxf(lmax, v[i]);
#pragma unroll
    for (int off = 32; off; off >>= 1) lmax = fmaxf(lmax, __shfl_down(lmax, off));
    if (lane == 0) lds[wave] = lmax;
    __syncthreads();
    const float gmax = fmaxf(fmaxf(lds[0], lds[1]), fmaxf(lds[2], lds[3]));
    __syncthreads();

    const float invT = (float)(1.0 / 22.627416997969522);
    float lsum = 0.f;
#pragma unroll
    for (int i = 0; i < 16; ++i) { v[i] = expf((v[i] - gmax) * invT); lsum += v[i]; }
#pragma unroll
    for (int off = 32; off; off >>= 1) lsum += __shfl_down(lsum, off);
    if (lane == 0) lds[wave] = lsum;
    __syncthreads();
    const float p0 = expf((s0 - gmax) * invT);
    const float gsum = lds[0] + lds[1] + lds[2] + lds[3] + p0;
    const float inv = 1.f / gsum;

#pragma unroll
    for (int h = 0; h < 2; ++h) {
        unsigned o0 = (unsigned)f2bf(v[h*8+0] * inv) | ((unsigned)f2bf(v[h*8+1] * inv) << 16);
        unsigned o1 = (unsigned)f2bf(v[h*8+2] * inv) | ((unsigned)f2bf(v[h*8+3] * inv) << 16);
        unsigned o2 = (unsigned)f2bf(v[h*8+4] * inv) | ((unsigned)f2bf(v[h*8+5] * inv) << 16);
        unsigned o3 = (unsigned)f2bf(v[h*8+6] * inv) | ((unsigned)f2bf(v[h*8+7] * inv) << 16);
        reinterpret_cast<uint4*>(row)[h == 0 ? t : t + 256] = (uint4){o0, o1, o2, o3};
    }
    if (t == 0) w0[n] = p0 * inv;
}

// ---------- epilogue: LN(w0*v_value + sum_z O_z + v_code) ----------
__global__ __launch_bounds__(256)
void final_ln(const u16* __restrict__ O /* KSPLIT bf16 slices */,
              const float* __restrict__ vval,
              const float* __restrict__ w0, const float* __restrict__ vcode,
              const float* __restrict__ gamma, const float* __restrict__ beta,
              float* __restrict__ out) {
    __shared__ float lds[8];
    const int n = blockIdx.x, t = threadIdx.x;
    const int lane = t & 63, wave = t >> 6;
    const size_t base = (size_t)n * E_DIM;
    const size_t NE = (size_t)N_ROWS * E_DIM;
    const float a = w0[n];

    float o0 = 0.f, o1 = 0.f;
#pragma unroll
    for (int z = 0; z < KSPLIT; ++z) {
        o0 += bf2f(O[z * NE + base + t]);
        o1 += bf2f(O[z * NE + base + t + 256]);
    }
    float x0 = fmaf(a, vval[base + t],       o0) + vcode[base + t];
    float x1 = fmaf(a, vval[base + t + 256], o1) + vcode[base + t + 256];

    float s = x0 + x1;
#pragma unroll
    for (int off = 32; off; off >>= 1) s += __shfl_down(s, off);
    if (lane == 0) lds[wave] = s;
    __syncthreads();
    const float mu = (lds[0] + lds[1] + lds[2] + lds[3]) * (1.0f / E_DIM);
    __syncthreads();

    const float d0 = x0 - mu, d1 = x1 - mu;
    float vs = d0 * d0 + d1 * d1;
#pragma unroll
    for (int off = 32; off; off >>= 1) vs += __shfl_down(vs, off);
    if (lane == 0) lds[wave] = vs;
    __syncthreads();
    const float var = (lds[0] + lds[1] + lds[2] + lds[3]) * (1.0f / E_DIM);
    const float rs = rsqrtf(var + 1e-6f);

    out[base + t]       = d0 * rs * gamma[t]       + beta[t];
    out[base + t + 256] = d1 * rs * gamma[t + 256] + beta[t + 256];
}

// ---------- workspace layout (bytes; total ~150 MiB) ----------
#define OFF_VCODEBF 0ull
#define OFF_OBSBF   8388608ull
#define OFF_WQ      12582912ull
#define OFF_WK      13107200ull
#define OFF_WV      13631488ull
#define OFF_WQT     14155776ull
#define OFF_WKT     14680064ull
#define OFF_WQKT    15204352ull
#define OFF_TBF     15728640ull
#define OFF_OBSV    24117248ull
#define OFF_OBSVT   28311552ull
#define OFF_VVAL    32505856ull
#define OFF_S       49283072ull
#define OFF_O       116391936ull
#define OFF_W0      149946368ull
#define OFF_SELF    149979136ull

extern "C" void kernel_launch(void* const* d_in, const int* in_sizes, int n_in,
                              void* d_out, int out_size, void* d_ws, size_t ws_size,
                              hipStream_t stream) {
    const float* v_code   = (const float*)d_in[0];
    const float* obs_code = (const float*)d_in[1];
    const float* Wq       = (const float*)d_in[2];
    const float* Wk       = (const float*)d_in[3];
    const float* Wv       = (const float*)d_in[4];
    const float* gamma    = (const float*)d_in[5];
    const float* beta     = (const float*)d_in[6];
    float* out = (float*)d_out;
    char* ws = (char*)d_ws;

    u16* vcode_bf = (u16*)(ws + OFF_VCODEBF);
    u16* obs_bf   = (u16*)(ws + OFF_OBSBF);
    u16* wq_bf    = (u16*)(ws + OFF_WQ);
    u16* wk_bf    = (u16*)(ws + OFF_WK);
    u16* wv_bf    = (u16*)(ws + OFF_WV);
    u16* wqT      = (u16*)(ws + OFF_WQT);
    u16* wkT      = (u16*)(ws + OFF_WKT);
    u16* wqkT     = (u16*)(ws + OFF_WQKT);
    u16* t_bf     = (u16*)(ws + OFF_TBF);
    u16* obsv_bf  = (u16*)(ws + OFF_OBSV);
    u16* obsvT_bf = (u16*)(ws + OFF_OBSVT);
    float* vval   = (float*)(ws + OFF_VVAL);
    u16* S        = (u16*)(ws + OFF_S);
    u16* O        = (u16*)(ws + OFF_O);
    float* w0     = (float*)(ws + OFF_W0);
    float* selfS  = (float*)(ws + OFF_SELF);

    // 1. casts
    cast_bf<<<N_ROWS * E_DIM / 4 / 256, 256, 0, stream>>>(v_code, vcode_bf, N_ROWS * E_DIM / 4);
    cast_bf<<<M_ROWS * E_DIM / 4 / 256, 256, 0, stream>>>(obs_code, obs_bf, M_ROWS * E_DIM / 4);
    cast_bf<<<E_DIM * E_DIM / 4 / 256, 256, 0, stream>>>(Wq, wq_bf, E_DIM * E_DIM / 4);
    cast_bf<<<E_DIM * E_DIM / 4 / 256, 256, 0, stream>>>(Wk, wk_bf, E_DIM * E_DIM / 4);
    cast_bf<<<E_DIM * E_DIM / 4 / 256, 256, 0, stream>>>(Wv, wv_bf, E_DIM * E_DIM / 4);

    // 2. transpose Wq, Wk (512x512 each)
    transpose_bf<<<dim3(8, 8), 256, 0, stream>>>(wq_bf, wqT, E_DIM, E_DIM);
    transpose_bf<<<dim3(8, 8), 256, 0, stream>>>(wk_bf, wkT, E_DIM, E_DIM);

    // 3. WqkT = (Wq^T Wk)^T = gemm_bt(WkT, WqT)  [512x512]
    gemm_main<<<dim3(E_DIM / 256, E_DIM / 128, 1), 256, 0, stream>>>(
        wkT, E_DIM, wqT, E_DIM, wqkT, E_DIM, E_DIM, 0, 1);

    // 4. projections: vval = vcode@Wv^T (fp32), obsv = obs@Wv^T (bf16), T = vcode@Wqk (bf16)
    ProjArgs p;
    p.A[0] = vcode_bf; p.B[0] = wv_bf; p.C[0] = vval;    p.rows[0] = N_ROWS; p.mode[0] = 0; p.ldc[0] = E_DIM;
    p.A[1] = obs_bf;   p.B[1] = wv_bf; p.C[1] = obsv_bf; p.rows[1] = M_ROWS; p.mode[1] = 1; p.ldc[1] = E_DIM;
    p.A[2] = vcode_bf; p.B[2] = wqkT;  p.C[2] = t_bf;    p.rows[2] = N_ROWS; p.mode[2] = 1; p.ldc[2] = E_DIM;
    proj_gemm<<<dim3(E_DIM / 256, N_ROWS / 128, 3), 256, 0, stream>>>(p);

    // 5. transpose obsv -> obsvT [512 x 4096]
    transpose_bf<<<dim3(E_DIM / 64, M_ROWS / 64), 256, 0, stream>>>(obsv_bf, obsvT_bf, M_ROWS, E_DIM);

    // 6. self score: dot(T[n], vcode[n])
    self_dot<<<N_ROWS / 4, 256, 0, stream>>>(t_bf, vcode_bf, selfS);

    // 7. cross scores S = T @ obs^T  [8192 x 4096], bf16 out
    gemm_main<<<dim3(M_ROWS / 256, N_ROWS / 128, 1), 256, 0, stream>>>(
        t_bf, E_DIM, obs_bf, E_DIM, S, M_ROWS, E_DIM, 0, 1);

    // 8. softmax -> bf16 weights in place
    softmax_row_bf<<<N_ROWS, 256, 0, stream>>>(S, selfS, w0);

    // 9. O_z = W[:, z-slice] @ V_obs[z-slice, :]  (split-K=4, bf16 slices; 128x256 tiles)
    gemm_main<<<dim3(E_DIM / 256, N_ROWS / 128, KSPLIT), 256, 0, stream>>>(
        S, M_ROWS, obsvT_bf, M_ROWS, O, E_DIM, M_ROWS / KSPLIT,
        (long long)N_ROWS * E_DIM * 2, 1);

    // 10. residual + LayerNorm (sums the KSPLIT PV slices)
    final_ln<<<N_ROWS, 256, 0, stream>>>(O, vval, w0, v_code, gamma, beta, out);
}

// Round 6
// 266.422 us; speedup vs baseline: 1.2454x; 1.0788x over previous
//
#include <hip/hip_runtime.h>
#include <hip/hip_bf16.h>

typedef unsigned short u16;
typedef __bf16 bf16x8 __attribute__((ext_vector_type(8)));
typedef float f32x4 __attribute__((ext_vector_type(4)));

#define N_ROWS 8192
#define M_ROWS 4096
#define E_DIM  512
#define KSPLIT 4
#define INV_T  0.04419417382415922f   // 1/sqrt(512)... = 1/22.627416997969522

// ---------- helpers ----------
__device__ __forceinline__ u16 f2bf(float f) {
    unsigned u = __float_as_uint(f);
    u += 0x7FFF + ((u >> 16) & 1);   // RNE
    return (u16)(u >> 16);
}
__device__ __forceinline__ float bf2f(u16 u) {
    return __uint_as_float(((unsigned)u) << 16);
}

#define GLD16(gp, lp) \
    __builtin_amdgcn_global_load_lds((const __attribute__((address_space(1))) void*)(gp), \
                                     (__attribute__((address_space(3))) void*)(lp), 16, 0, 0)

// ---------- cast fp32 -> bf16, 4 elems/thread ----------
__global__ __launch_bounds__(256)
void cast_bf(const float* __restrict__ in, u16* __restrict__ out, int n4) {
    int i = blockIdx.x * 256 + threadIdx.x;
    if (i < n4) {
        float4 f = reinterpret_cast<const float4*>(in)[i];
        ushort4 o;
        o.x = f2bf(f.x); o.y = f2bf(f.y); o.z = f2bf(f.z); o.w = f2bf(f.w);
        reinterpret_cast<ushort4*>(out)[i] = o;
    }
}

// ---------- bf16 tiled transpose: out[c][r] = in[r][c]; R,C multiples of 64 ----------
__global__ __launch_bounds__(256)
void transpose_bf(const u16* __restrict__ in, u16* __restrict__ out, int R, int C) {
    __shared__ u16 t[64][72];
    const int r0 = blockIdx.y * 64, c0 = blockIdx.x * 64;
    const int tid = threadIdx.x;
    const int lr = tid >> 2, lc = (tid & 3) * 16;
    const u16* src = in + (size_t)(r0 + lr) * C + c0 + lc;
    *reinterpret_cast<uint4*>(&t[lr][lc])     = *reinterpret_cast<const uint4*>(src);
    *reinterpret_cast<uint4*>(&t[lr][lc + 8]) = *reinterpret_cast<const uint4*>(src + 8);
    __syncthreads();
    u16 tmp[16];
#pragma unroll
    for (int j = 0; j < 16; ++j) tmp[j] = t[lc + j][lr];
    u16* dst = out + (size_t)(c0 + lr) * R + r0 + lc;
    *reinterpret_cast<uint4*>(dst)     = *reinterpret_cast<uint4*>(&tmp[0]);
    *reinterpret_cast<uint4*>(dst + 8) = *reinterpret_cast<uint4*>(&tmp[8]);
}

// ---------- 128x256 MFMA GEMM body, single-barrier double-buffered pipeline ----------
// C[i][j] = sum_k A[i][k]*B[j][k]; A,B bf16 K-contiguous.
// Per wave: 64 rows x 128 cols = 4x8 fragments, 32 MFMA / K-step.
// mode: 0 = fp32 row-major, 1 = bf16 row-major,
//       2 = bf16 exp(acc*INV_T) + per-row partial sums into psum (unnormalized softmax fusion)
__device__ __forceinline__
void gemm_wide_body(const u16* __restrict__ A, int lda,
                    const u16* __restrict__ B, int ldb,
                    void* __restrict__ C, int ldc, int K,
                    int row0, int col0, int mode,
                    float* __restrict__ psum /* base for this block's 2 partial cols */) {
    __shared__ u16 sA[2][128 * 32];   // 8 KB per buffer
    __shared__ u16 sB[2][256 * 32];   // 16 KB per buffer

    const int tid  = threadIdx.x;
    const int wave = tid >> 6, lane = tid & 63;
    const int quad = lane >> 4, m16 = lane & 15;
    const int wr = (wave & 1) * 64;       // wave's 64-row half
    const int wc = (wave >> 1) * 128;     // wave's 128-col half

    const int srow  = lane >> 2;
    const int skoff = (lane & 3) * 8;
    const u16* ag0 = A + (size_t)(row0 + wave * 16 + srow) * lda + skoff;
    const u16* ag1 = ag0 + (size_t)64 * lda;
    const u16* bg0 = B + (size_t)(col0 + wave * 16 + srow) * ldb + skoff;
    const u16* bg1 = bg0 + (size_t)64 * ldb;
    const u16* bg2 = bg0 + (size_t)128 * ldb;
    const u16* bg3 = bg0 + (size_t)192 * ldb;
    const int loa0 = (wave * 16) * 32;
    const int loa1 = (wave * 16 + 64) * 32;
    const int lob0 = (wave * 16) * 32;
    const int lob1 = (wave * 16 + 64) * 32;
    const int lob2 = (wave * 16 + 128) * 32;
    const int lob3 = (wave * 16 + 192) * 32;

    f32x4 acc[4][8];
#pragma unroll
    for (int i = 0; i < 4; ++i)
#pragma unroll
        for (int j = 0; j < 8; ++j) acc[i][j] = (f32x4){0.f, 0.f, 0.f, 0.f};

    // prologue: stage k=0 into buffer 0
    GLD16(ag0, &sA[0][loa0]); GLD16(ag1, &sA[0][loa1]);
    GLD16(bg0, &sB[0][lob0]); GLD16(bg1, &sB[0][lob1]);
    GLD16(bg2, &sB[0][lob2]); GLD16(bg3, &sB[0][lob3]);

    int kb = 0;
    for (int k0 = 0; k0 < K; k0 += 32, kb ^= 1) {
        __syncthreads();   // buf[kb] data landed; prior reads of buf[kb^1] done
        const int kn = (k0 + 32 < K) ? (k0 + 32) : 0;   // last iter: harmless reload
        GLD16(ag0 + kn, &sA[kb ^ 1][loa0]); GLD16(ag1 + kn, &sA[kb ^ 1][loa1]);
        GLD16(bg0 + kn, &sB[kb ^ 1][lob0]); GLD16(bg1 + kn, &sB[kb ^ 1][lob1]);
        GLD16(bg2 + kn, &sB[kb ^ 1][lob2]); GLD16(bg3 + kn, &sB[kb ^ 1][lob3]);

        bf16x8 a[4], b[8];
#pragma unroll
        for (int i = 0; i < 4; ++i)
            a[i] = *reinterpret_cast<const bf16x8*>(&sA[kb][(wr + i * 16 + m16) * 32 + quad * 8]);
#pragma unroll
        for (int j = 0; j < 8; ++j)
            b[j] = *reinterpret_cast<const bf16x8*>(&sB[kb][(wc + j * 16 + m16) * 32 + quad * 8]);
#pragma unroll
        for (int i = 0; i < 4; ++i)
#pragma unroll
            for (int j = 0; j < 8; ++j)
                acc[i][j] = __builtin_amdgcn_mfma_f32_16x16x32_bf16(a[i], b[j], acc[i][j], 0, 0, 0);
    }

    // epilogue: C/D layout col=lane&15, row=quad*4+r (HW-verified)
    if (mode == 2) {
        // exp + bf16 store + per-row partial sums (no max subtraction: fp32 can't overflow here)
        float* pcol = psum + (size_t)(wave >> 1) * N_ROWS;  // waves {0,1}->col0, {2,3}->col1
#pragma unroll
        for (int i = 0; i < 4; ++i) {
            const int rbase = row0 + wr + i * 16 + quad * 4;
            float rs[4] = {0.f, 0.f, 0.f, 0.f};
#pragma unroll
            for (int j = 0; j < 8; ++j) {
                const int c = col0 + wc + j * 16 + m16;
#pragma unroll
                for (int r = 0; r < 4; ++r) {
                    const float v = __expf(acc[i][j][r] * INV_T);
                    rs[r] += v;
                    reinterpret_cast<u16*>(C)[(size_t)(rbase + r) * ldc + c] = f2bf(v);
                }
            }
#pragma unroll
            for (int r = 0; r < 4; ++r) {
                float s = rs[r];
                s += __shfl_down(s, 8, 16);
                s += __shfl_down(s, 4, 16);
                s += __shfl_down(s, 2, 16);
                s += __shfl_down(s, 1, 16);
                if (m16 == 0) pcol[rbase + r] = s;
            }
        }
    } else {
#pragma unroll
        for (int i = 0; i < 4; ++i) {
            const int rbase = row0 + wr + i * 16 + quad * 4;
#pragma unroll
            for (int j = 0; j < 8; ++j) {
                const int c = col0 + wc + j * 16 + m16;
#pragma unroll
                for (int r = 0; r < 4; ++r) {
                    const float v = acc[i][j][r];
                    const int rr = rbase + r;
                    if (mode == 0) {
                        reinterpret_cast<float*>(C)[(size_t)rr * ldc + c] = v;
                    } else {
                        reinterpret_cast<u16*>(C)[(size_t)rr * ldc + c] = f2bf(v);
                    }
                }
            }
        }
    }
}

// ---------- batched projection GEMMs (grid.z picks descriptor) ----------
struct ProjArgs {
    const u16* A[3];
    const u16* B[3];
    void*      C[3];
    int        rows[3];
    int        mode[3];
    int        ldc[3];
};

__global__ __launch_bounds__(256, 2)
void proj_gemm(ProjArgs p) {
    const int z = blockIdx.z;
    const int row0 = blockIdx.y * 128;
    if (row0 >= p.rows[z]) return;
    gemm_wide_body(p.A[z], E_DIM, p.B[z], E_DIM, p.C[z], p.ldc[z], E_DIM,
                   row0, blockIdx.x * 256, p.mode[z], nullptr);
}

// ---------- main GEMM (score w/ fused exp, PV w/ split-K over grid.z) ----------
__global__ __launch_bounds__(256, 2)
void gemm_main(const u16* __restrict__ A, int lda,
               const u16* __restrict__ B, int ldb,
               void* __restrict__ C, int ldc, int Kslice,
               long long cstride_bytes, int mode, float* __restrict__ psum) {
    const int z = blockIdx.z;
    const u16* Az = A + (long long)z * Kslice;
    const u16* Bz = B + (long long)z * Kslice;
    void* Cz = (char*)C + (long long)z * cstride_bytes;
    float* ps = psum ? psum + (size_t)(blockIdx.x * 2) * N_ROWS : nullptr;
    gemm_wide_body(Az, lda, Bz, ldb, Cz, ldc, Kslice,
                   blockIdx.y * 128, blockIdx.x * 256, mode, ps);
}

// ---------- self attention score: dot(T[n], vcode[n]) ----------
__global__ __launch_bounds__(256)
void self_dot(const u16* __restrict__ q, const u16* __restrict__ k,
              float* __restrict__ selfS) {
    const int wave = threadIdx.x >> 6, lane = threadIdx.x & 63;
    const int row = blockIdx.x * 4 + wave;
    const uint4 qa = *reinterpret_cast<const uint4*>(q + (size_t)row * E_DIM + lane * 8);
    const uint4 ka = *reinterpret_cast<const uint4*>(k + (size_t)row * E_DIM + lane * 8);
    unsigned qu[4] = {qa.x, qa.y, qa.z, qa.w};
    unsigned ku[4] = {ka.x, ka.y, ka.z, ka.w};
    float s = 0.f;
#pragma unroll
    for (int i = 0; i < 4; ++i) {
        s += bf2f((u16)(qu[i] & 0xFFFF)) * bf2f((u16)(ku[i] & 0xFFFF));
        s += bf2f((u16)(qu[i] >> 16))    * bf2f((u16)(ku[i] >> 16));
    }
#pragma unroll
    for (int off = 32; off; off >>= 1) s += __shfl_down(s, off);
    if (lane == 0) selfS[row] = s;
}

// ---------- combine partial row sums -> inv_l, p0 ----------
__global__ __launch_bounds__(256)
void sum_combine(const float* __restrict__ psum, const float* __restrict__ selfS,
                 float* __restrict__ p0_out, float* __restrict__ invl_out) {
    const int n = blockIdx.x * 256 + threadIdx.x;
    float l = 0.f;
#pragma unroll
    for (int j = 0; j < 32; ++j) l += psum[(size_t)j * N_ROWS + n];
    const float p0 = expf(selfS[n] * INV_T);
    l += p0;
    p0_out[n] = p0;
    invl_out[n] = 1.f / l;
}

// ---------- epilogue: LN(inv_l*(p0*v_value + sum_z O_z) + v_code) ----------
__global__ __launch_bounds__(256)
void final_ln(const u16* __restrict__ O /* KSPLIT bf16 slices */,
              const u16* __restrict__ vval /* bf16 */,
              const float* __restrict__ p0v, const float* __restrict__ invl,
              const float* __restrict__ vcode,
              const float* __restrict__ gamma, const float* __restrict__ beta,
              float* __restrict__ out) {
    __shared__ float lds[8];
    const int n = blockIdx.x, t = threadIdx.x;
    const int lane = t & 63, wave = t >> 6;
    const size_t base = (size_t)n * E_DIM;
    const size_t NE = (size_t)N_ROWS * E_DIM;
    const float a = p0v[n], il = invl[n];

    float o0 = 0.f, o1 = 0.f;
#pragma unroll
    for (int z = 0; z < KSPLIT; ++z) {
        o0 += bf2f(O[z * NE + base + t]);
        o1 += bf2f(O[z * NE + base + t + 256]);
    }
    float x0 = fmaf(a, bf2f(vval[base + t]),       o0) * il + vcode[base + t];
    float x1 = fmaf(a, bf2f(vval[base + t + 256]), o1) * il + vcode[base + t + 256];

    float s = x0 + x1;
#pragma unroll
    for (int off = 32; off; off >>= 1) s += __shfl_down(s, off);
    if (lane == 0) lds[wave] = s;
    __syncthreads();
    const float mu = (lds[0] + lds[1] + lds[2] + lds[3]) * (1.0f / E_DIM);
    __syncthreads();

    const float d0 = x0 - mu, d1 = x1 - mu;
    float vs = d0 * d0 + d1 * d1;
#pragma unroll
    for (int off = 32; off; off >>= 1) vs += __shfl_down(vs, off);
    if (lane == 0) lds[wave] = vs;
    __syncthreads();
    const float var = (lds[0] + lds[1] + lds[2] + lds[3]) * (1.0f / E_DIM);
    const float rs = rsqrtf(var + 1e-6f);

    out[base + t]       = d0 * rs * gamma[t]       + beta[t];
    out[base + t + 256] = d1 * rs * gamma[t + 256] + beta[t + 256];
}

// ---------- workspace layout (bytes; total ~152 MiB) ----------
#define OFF_VCODEBF 0ull
#define OFF_OBSBF   8388608ull
#define OFF_WQ      12582912ull
#define OFF_WK      13107200ull
#define OFF_WV      13631488ull
#define OFF_WQT     14155776ull
#define OFF_WKT     14680064ull
#define OFF_WQKT    15204352ull
#define OFF_TBF     15728640ull
#define OFF_OBSV    24117248ull
#define OFF_OBSVT   28311552ull
#define OFF_VVAL    32505856ull      // bf16 now: 8 MiB
#define OFF_S       49283072ull      // holds unnormalized P~ (bf16, 64 MiB)
#define OFF_O       116391936ull     // KSPLIT bf16 slices (32 MiB)
#define OFF_P0      149946368ull
#define OFF_SELF    149979136ull
#define OFF_INVL    150011904ull
#define OFF_PSUM    150044672ull     // 32 x 8192 fp32 = 1 MiB

extern "C" void kernel_launch(void* const* d_in, const int* in_sizes, int n_in,
                              void* d_out, int out_size, void* d_ws, size_t ws_size,
                              hipStream_t stream) {
    const float* v_code   = (const float*)d_in[0];
    const float* obs_code = (const float*)d_in[1];
    const float* Wq       = (const float*)d_in[2];
    const float* Wk       = (const float*)d_in[3];
    const float* Wv       = (const float*)d_in[4];
    const float* gamma    = (const float*)d_in[5];
    const float* beta     = (const float*)d_in[6];
    float* out = (float*)d_out;
    char* ws = (char*)d_ws;

    u16* vcode_bf = (u16*)(ws + OFF_VCODEBF);
    u16* obs_bf   = (u16*)(ws + OFF_OBSBF);
    u16* wq_bf    = (u16*)(ws + OFF_WQ);
    u16* wk_bf    = (u16*)(ws + OFF_WK);
    u16* wv_bf    = (u16*)(ws + OFF_WV);
    u16* wqT      = (u16*)(ws + OFF_WQT);
    u16* wkT      = (u16*)(ws + OFF_WKT);
    u16* wqkT     = (u16*)(ws + OFF_WQKT);
    u16* t_bf     = (u16*)(ws + OFF_TBF);
    u16* obsv_bf  = (u16*)(ws + OFF_OBSV);
    u16* obsvT_bf = (u16*)(ws + OFF_OBSVT);
    u16* vval     = (u16*)(ws + OFF_VVAL);
    u16* S        = (u16*)(ws + OFF_S);
    u16* O        = (u16*)(ws + OFF_O);
    float* p0v    = (float*)(ws + OFF_P0);
    float* selfS  = (float*)(ws + OFF_SELF);
    float* invl   = (float*)(ws + OFF_INVL);
    float* psum   = (float*)(ws + OFF_PSUM);

    // 1. casts
    cast_bf<<<N_ROWS * E_DIM / 4 / 256, 256, 0, stream>>>(v_code, vcode_bf, N_ROWS * E_DIM / 4);
    cast_bf<<<M_ROWS * E_DIM / 4 / 256, 256, 0, stream>>>(obs_code, obs_bf, M_ROWS * E_DIM / 4);
    cast_bf<<<E_DIM * E_DIM / 4 / 256, 256, 0, stream>>>(Wq, wq_bf, E_DIM * E_DIM / 4);
    cast_bf<<<E_DIM * E_DIM / 4 / 256, 256, 0, stream>>>(Wk, wk_bf, E_DIM * E_DIM / 4);
    cast_bf<<<E_DIM * E_DIM / 4 / 256, 256, 0, stream>>>(Wv, wv_bf, E_DIM * E_DIM / 4);

    // 2. transpose Wq, Wk (512x512 each)
    transpose_bf<<<dim3(8, 8), 256, 0, stream>>>(wq_bf, wqT, E_DIM, E_DIM);
    transpose_bf<<<dim3(8, 8), 256, 0, stream>>>(wk_bf, wkT, E_DIM, E_DIM);

    // 3. WqkT = (Wq^T Wk)^T = gemm_bt(WkT, WqT)  [512x512]
    gemm_main<<<dim3(E_DIM / 256, E_DIM / 128, 1), 256, 0, stream>>>(
        wkT, E_DIM, wqT, E_DIM, wqkT, E_DIM, E_DIM, 0, 1, nullptr);

    // 4. projections: vval = vcode@Wv^T (bf16), obsv = obs@Wv^T (bf16), T = vcode@Wqk (bf16)
    ProjArgs p;
    p.A[0] = vcode_bf; p.B[0] = wv_bf; p.C[0] = vval;    p.rows[0] = N_ROWS; p.mode[0] = 1; p.ldc[0] = E_DIM;
    p.A[1] = obs_bf;   p.B[1] = wv_bf; p.C[1] = obsv_bf; p.rows[1] = M_ROWS; p.mode[1] = 1; p.ldc[1] = E_DIM;
    p.A[2] = vcode_bf; p.B[2] = wqkT;  p.C[2] = t_bf;    p.rows[2] = N_ROWS; p.mode[2] = 1; p.ldc[2] = E_DIM;
    proj_gemm<<<dim3(E_DIM / 256, N_ROWS / 128, 3), 256, 0, stream>>>(p);

    // 5. transpose obsv -> obsvT [512 x 4096]
    transpose_bf<<<dim3(E_DIM / 64, M_ROWS / 64), 256, 0, stream>>>(obsv_bf, obsvT_bf, M_ROWS, E_DIM);

    // 6. self score: dot(T[n], vcode[n])
    self_dot<<<N_ROWS / 4, 256, 0, stream>>>(t_bf, vcode_bf, selfS);

    // 7. scores + fused exp: P~ = exp((T @ obs^T)/T) bf16, partial row sums -> psum[32][8192]
    gemm_main<<<dim3(M_ROWS / 256, N_ROWS / 128, 1), 256, 0, stream>>>(
        t_bf, E_DIM, obs_bf, E_DIM, S, M_ROWS, E_DIM, 0, 2, psum);

    // 8. combine partials + self term -> p0, 1/l
    sum_combine<<<N_ROWS / 256, 256, 0, stream>>>(psum, selfS, p0v, invl);

    // 9. O_z = P~[:, z-slice] @ V_obs[z-slice, :]  (split-K=4, bf16 slices; 128x256 tiles)
    gemm_main<<<dim3(E_DIM / 256, N_ROWS / 128, KSPLIT), 256, 0, stream>>>(
        S, M_ROWS, obsvT_bf, M_ROWS, O, E_DIM, M_ROWS / KSPLIT,
        (long long)N_ROWS * E_DIM * 2, 1, nullptr);

    // 10. residual + LayerNorm (normalizes by 1/l, sums the KSPLIT PV slices)
    final_ln<<<N_ROWS, 256, 0, stream>>>(O, vval, p0v, invl, v_code, gamma, beta, out);
}